// Round 7
// baseline (739.877 us; speedup 1.0000x reference)
//
#include <hip/hip_runtime.h>
#include <hip/hip_bf16.h>

#define I_SZ 834
#define H_SZ 190
#define F_SZ 250
#define O_SZ 512
#define T_SZ 256
#define K_SZ 1024   // I+H
#define NW   47500  // F*H: Wupd flat IS W3[1024][47500] row-major

// Abf2 layout: value A[t][k] (bf16 of concat(x_t,h_t)) lives at
//   (k>>3)*2048 + t*8 + (k&7)   -> b128 fragment loads are 256-B coalesced.

typedef __attribute__((ext_vector_type(8))) short short8;
typedef __attribute__((ext_vector_type(4))) float f32x4;

__device__ __forceinline__ short f2bf(float f) {
    union { __hip_bfloat16 h; short s; } u;
    u.h = __float2bfloat16(f);
    return u.s;
}

// -------- K2b: x-part of Abf2 + zero pad k in [834,864) ---------------------
__global__ void __launch_bounds__(256) k2b_buildAx(const float* __restrict__ x,
                                                   short* __restrict__ Abf2) {
    int t = blockIdx.x;
    for (int i = threadIdx.x; i < I_SZ; i += 256)
        Abf2[(i >> 3) * (T_SZ * 8) + t * 8 + (i & 7)] = f2bf(x[t * I_SZ + i]);
    for (int i = I_SZ + threadIdx.x; i < 864; i += 256)
        Abf2[(i >> 3) * (T_SZ * 8) + t * 8 + (i & 7)] = 0;
}

// -------- K1: P^T[h][t] = Wx^T @ x^T via MFMA (12 blocks x 4 waves) ---------
__global__ void __launch_bounds__(256) k1_mfma(const short* __restrict__ Abf2,
                                               const float* __restrict__ Wrnn,
                                               const float* __restrict__ brnn,
                                               float* __restrict__ P) {
    const int tid = threadIdx.x;
    const int bh = blockIdx.x;
    const int w = tid >> 6, l = tid & 63;
    const int l15 = l & 15, lg = l >> 4;
    const int h = bh * 16 + l15;
    const int hc = (h < H_SZ) ? h : H_SZ - 1;

    f32x4 acc[4];
    #pragma unroll
    for (int tt = 0; tt < 4; ++tt) acc[tt] = (f32x4){0.f, 0.f, 0.f, 0.f};

    for (int ks = 0; ks < 27; ++ks) {       // K = 864 (zero-padded past 834)
        short8 afr;
        #pragma unroll
        for (int e = 0; e < 8; ++e) {
            const int kk = ks * 32 + lg * 8 + e;
            float v = (kk < I_SZ && h < H_SZ) ? Wrnn[hc * K_SZ + H_SZ + kk] : 0.f;
            afr[e] = f2bf(v);
        }
        #pragma unroll
        for (int tt = 0; tt < 4; ++tt) {
            const short* ap = Abf2 + (size_t)(ks * 4 + lg) * (T_SZ * 8)
                                   + (size_t)(w * 64 + tt * 16 + l15) * 8;
            short8 bfr = *reinterpret_cast<const short8*>(ap);
            acc[tt] = __builtin_amdgcn_mfma_f32_16x16x32_bf16(afr, bfr, acc[tt], 0, 0, 0);
        }
    }
    #pragma unroll
    for (int tt = 0; tt < 4; ++tt) {
        const int t = w * 64 + tt * 16 + l15;
        #pragma unroll
        for (int r = 0; r < 4; ++r) {
            const int hrow = bh * 16 + lg * 4 + r;
            if (hrow < H_SZ) P[t * H_SZ + hrow] = acc[tt][r] + brnn[hrow];
        }
    }
}

// -------- K2: MFMA scan, 4 waves = 2(n) x 2(k); B[3][6] = 72 VGPR/wave ------
__global__ void __launch_bounds__(256, 1) k2_scan(const float* __restrict__ Wrnn,
                                                  const float* __restrict__ h0,
                                                  const float* __restrict__ P,
                                                  float* __restrict__ h_all,
                                                  float* __restrict__ S,
                                                  short* __restrict__ Abf2) {
    __shared__ __align__(16) short hlds[192];
    __shared__ float part[2][192];
    const int tid = threadIdx.x;
    const int w = tid >> 6, l = tid & 63;
    const int wn = w & 1, wk = w >> 1;
    const int l15 = l & 15, lg = l >> 4;
    const short8 zs = {0, 0, 0, 0, 0, 0, 0, 0};

    short8 B[3][6];
    #pragma unroll
    for (int kt = 0; kt < 3; ++kt) {
        #pragma unroll
        for (int nt = 0; nt < 6; ++nt) {
            const int n = wn * 96 + nt * 16 + l15;
            short8 bf = zs;
            #pragma unroll
            for (int e = 0; e < 8; ++e) {
                const int kk = wk * 96 + kt * 32 + lg * 8 + e;
                float v = (n < H_SZ && kk < H_SZ) ? Wrnn[n * K_SZ + kk] : 0.f;
                bf[e] = f2bf(v);
            }
            B[kt][nt] = bf;
        }
    }
    if (tid < 192) hlds[tid] = f2bf((tid < H_SZ) ? h0[tid] : 0.f);
    float Srun = 0.f;
    float pc = (tid < H_SZ) ? P[tid] : 0.f;
    __syncthreads();

    for (int t = 0; t < T_SZ; ++t) {
        short8 a[3];
        #pragma unroll
        for (int kt = 0; kt < 3; ++kt) {
            short8 ar = *reinterpret_cast<const short8*>(&hlds[wk * 96 + kt * 32 + lg * 8]);
            a[kt] = (l15 == 0) ? ar : zs;
        }
        float pn = (t + 1 < T_SZ && tid < H_SZ) ? P[(t + 1) * H_SZ + tid] : 0.f;
        f32x4 acc[6];
        #pragma unroll
        for (int nt = 0; nt < 6; ++nt) {
            f32x4 c = {0.f, 0.f, 0.f, 0.f};
            #pragma unroll
            for (int kt = 0; kt < 3; ++kt)
                c = __builtin_amdgcn_mfma_f32_16x16x32_bf16(a[kt], B[kt][nt], c, 0, 0, 0);
            acc[nt] = c;
        }
        if (l < 16) {
            #pragma unroll
            for (int nt = 0; nt < 6; ++nt)
                part[wk][wn * 96 + nt * 16 + l] = acc[nt][0];
        }
        __syncthreads();
        if (tid < H_SZ) {
            float v = tanhf(part[0][tid] + part[1][tid] + pc);
            S[t * H_SZ + tid] = Srun;            // prefix EXCLUDING current step
            h_all[t * H_SZ + tid] = v;
            const int k = I_SZ + tid;
            Abf2[(k >> 3) * (T_SZ * 8) + t * 8 + (k & 7)] = f2bf(v);
            hlds[tid] = f2bf(v);
            Srun += v;
        }
        pc = pn;
        __syncthreads();
    }
}

// -------- K3 v4: LDS-staged MFMA GEMM, depth-2 prefetch, 1 barrier/stage ----
// Block: 64 n-cols, 256 t. 8 waves = 4(wn) x 2(wt). BK=64, 16 stages.
// LDS W-tile [2][64][65] fp32; b32 access everywhere (stride 65 => <=2-way).
__global__ void __launch_bounds__(512) k3_mfma(const float* __restrict__ Wupd,
                                               const short* __restrict__ Abf2,
                                               const float* __restrict__ S,
                                               float* __restrict__ zprime) {
    __shared__ float Bs[2][64][65];
    const int tid = threadIdx.x;
    const int bn0 = blockIdx.x * 64;
    const int l = tid & 63, wv = tid >> 6;
    const int wn = wv & 3;              // n-tile 0..3
    const int wt = wv >> 2;             // t-half 0..1
    const int l15 = l & 15, lg = l >> 4;

    // staging geometry: thread -> rows (sk, sk+32), 4 cols at sc
    const int sk = tid >> 4;            // 0..31
    const int sc = (tid & 15) * 4;      // 0..60
    const bool sval = (bn0 + sc + 4) <= NW;     // NW % 4 == 0
    const float* wsrc = Wupd + (size_t)sk * NW + bn0 + sc;
    const float4 fz = make_float4(0.f, 0.f, 0.f, 0.f);

    float4 r0a, r0b, r1a, r1b;

#define K3_LOAD(RA, RB, STG) do {                                              \
        const float* _p = wsrc + (size_t)(STG) * 64 * NW;                      \
        RA = sval ? *reinterpret_cast<const float4*>(_p) : fz;                 \
        RB = sval ? *reinterpret_cast<const float4*>(_p + 32 * NW) : fz;       \
    } while (0)

#define K3_WRITE(RA, RB, BUFI) do {                                            \
        Bs[BUFI][sk][sc + 0] = RA.x;  Bs[BUFI][sk][sc + 1] = RA.y;             \
        Bs[BUFI][sk][sc + 2] = RA.z;  Bs[BUFI][sk][sc + 3] = RA.w;             \
        Bs[BUFI][sk + 32][sc + 0] = RB.x;  Bs[BUFI][sk + 32][sc + 1] = RB.y;   \
        Bs[BUFI][sk + 32][sc + 2] = RB.z;  Bs[BUFI][sk + 32][sc + 3] = RB.w;   \
    } while (0)

    f32x4 acc[8];
    #pragma unroll
    for (int tt = 0; tt < 8; ++tt) acc[tt] = (f32x4){0.f, 0.f, 0.f, 0.f};

#define K3_COMPUTE(BUFI, STG) do {                                             \
        _Pragma("unroll")                                                      \
        for (int kk = 0; kk < 2; ++kk) {                                       \
            short8 afr;                                                        \
            _Pragma("unroll")                                                  \
            for (int e = 0; e < 8; ++e)                                        \
                afr[e] = f2bf(Bs[BUFI][kk * 32 + lg * 8 + e][wn * 16 + l15]);  \
            const size_t slab = (size_t)(((STG) * 2 + kk) * 4 + lg) * (T_SZ * 8); \
            _Pragma("unroll")                                                  \
            for (int tt = 0; tt < 8; ++tt) {                                   \
                const short* ap = Abf2 + slab                                  \
                                + (size_t)(wt * 128 + tt * 16 + l15) * 8;      \
                short8 bfr = *reinterpret_cast<const short8*>(ap);             \
                acc[tt] = __builtin_amdgcn_mfma_f32_16x16x32_bf16(afr, bfr, acc[tt], 0, 0, 0); \
            }                                                                  \
        }                                                                      \
    } while (0)

    // prologue: f0 -> buf0, issue f1
    K3_LOAD(r0a, r0b, 0);
    K3_WRITE(r0a, r0b, 0);              // compiler inserts vmcnt wait
    K3_LOAD(r1a, r1b, 1);
    __syncthreads();

    #pragma unroll 1
    for (int s = 0; s < 16; s += 2) {
        // even stage s: write f_{s+1} -> buf1, issue f_{s+2}, compute buf0
        K3_WRITE(r1a, r1b, 1);
        if (s < 14) K3_LOAD(r0a, r0b, s + 2);
        K3_COMPUTE(0, s);
        __syncthreads();
        // odd stage s+1: write f_{s+2} -> buf0, issue f_{s+3}, compute buf1
        if (s < 14) K3_WRITE(r0a, r0b, 0);
        if (s < 12) K3_LOAD(r1a, r1b, s + 3);
        K3_COMPUTE(1, s + 1);
        __syncthreads();
    }
#undef K3_LOAD
#undef K3_WRITE
#undef K3_COMPUTE

    // epilogue: z'[t][j] += sum_h C^T[n][t] * S[t][h(n)], bucketed by j
    const int jlo = bn0 / H_SZ;
    float pj[8][2];
    #pragma unroll
    for (int tt = 0; tt < 8; ++tt) { pj[tt][0] = 0.f; pj[tt][1] = 0.f; }
    #pragma unroll
    for (int r = 0; r < 4; ++r) {
        const int n = bn0 + wn * 16 + lg * 4 + r;
        const bool ok = n < NW;
        const int nc = ok ? n : NW - 1;
        const int j = nc / H_SZ;
        const int h = nc - j * H_SZ;
        const bool b0 = (j == jlo);
        #pragma unroll
        for (int tt = 0; tt < 8; ++tt) {
            const int t = wt * 128 + tt * 16 + l15;
            const float sv = S[t * H_SZ + h];
            const float prod = ok ? acc[tt][r] * sv : 0.f;
            pj[tt][0] += b0 ? prod : 0.f;
            pj[tt][1] += b0 ? 0.f : prod;
        }
    }
    #pragma unroll
    for (int tt = 0; tt < 8; ++tt) {
        #pragma unroll
        for (int b = 0; b < 2; ++b) {
            float v = pj[tt][b];
            v += __shfl_xor(v, 16, 64);
            v += __shfl_xor(v, 32, 64);
            if (lg == 0) {
                const int j = jlo + b;
                if (j < F_SZ) {
                    const int t = wt * 128 + tt * 16 + l15;
                    atomicAdd(&zprime[t * F_SZ + j], v);
                }
            }
        }
    }
}

// -------- K4: z -> selu -> @W2 + b2 -----------------------------------------
__global__ void __launch_bounds__(256) k4_out(const float* __restrict__ x,
                                              const float* __restrict__ h_all,
                                              const float* __restrict__ W1,
                                              const float* __restrict__ bupd,
                                              const float* __restrict__ b1,
                                              const float* __restrict__ W2,
                                              const float* __restrict__ b2,
                                              const float* __restrict__ zprime,
                                              float* __restrict__ out) {
    __shared__ float as[K_SZ];
    __shared__ float ys[256];
    int t = blockIdx.x;
    int tid = threadIdx.x;
    for (int i = tid; i < K_SZ; i += 256)
        as[i] = (i < I_SZ) ? x[t * I_SZ + i] : h_all[t * H_SZ + (i - I_SZ)];
    __syncthreads();
    if (tid < F_SZ) {
        float d1 = 0.f, d2 = 0.f;
        #pragma unroll 4
        for (int i = 0; i < K_SZ; ++i) {
            float av = as[i];
            d1 += av * W1[i * F_SZ + tid];
            d2 += av * bupd[i * F_SZ + tid];
        }
        float z = zprime[t * F_SZ + tid] + d1 + (float)t * d2 + b1[tid];
        const float scale = 1.0507009873554805f, alpha = 1.6732632423543772f;
        ys[tid] = z > 0.f ? scale * z : scale * alpha * (expf(z) - 1.f);
    }
    __syncthreads();
    #pragma unroll
    for (int rep = 0; rep < 2; ++rep) {
        int o = tid + rep * 256;
        float s = 0.f;
        #pragma unroll 2
        for (int jj = 0; jj < F_SZ; ++jj) s += ys[jj] * W2[jj * O_SZ + o];
        out[t * O_SZ + o] = s + b2[o];
    }
}

extern "C" void kernel_launch(void* const* d_in, const int* in_sizes, int n_in,
                              void* d_out, int out_size, void* d_ws, size_t ws_size,
                              hipStream_t stream) {
    const float* x    = (const float*)d_in[0];
    const float* h0   = (const float*)d_in[1];
    const float* Wrnn = (const float*)d_in[2];
    const float* brnn = (const float*)d_in[3];
    const float* Wupd = (const float*)d_in[4];
    const float* bupd = (const float*)d_in[5];
    const float* W1   = (const float*)d_in[6];
    const float* b1   = (const float*)d_in[7];
    const float* W2   = (const float*)d_in[8];
    const float* b2   = (const float*)d_in[9];
    float* out = (float*)d_out;

    float* ws = (float*)d_ws;
    float* P      = ws;                              // 48640
    float* h_all  = P + T_SZ * H_SZ;                 // 48640
    float* S      = h_all + T_SZ * H_SZ;             // 48640
    float* zprime = S + T_SZ * H_SZ;                 // 64000
    short* Abf2   = (short*)(zprime + T_SZ * F_SZ);  // 262144 shorts

    hipMemsetAsync(zprime, 0, T_SZ * F_SZ * sizeof(float), stream);
    k2b_buildAx<<<T_SZ, 256, 0, stream>>>(x, Abf2);
    k1_mfma    <<<12,   256, 0, stream>>>(Abf2, Wrnn, brnn, P);
    k2_scan    <<<1,    256, 0, stream>>>(Wrnn, h0, P, h_all, S, Abf2);
    k3_mfma    <<<743,  512, 0, stream>>>(Wupd, Abf2, S, zprime);
    k4_out     <<<T_SZ, 256, 0, stream>>>(x, h_all, W1, bupd, b1, W2, b2, zprime, out);
}

// Round 8
// 429.856 us; speedup vs baseline: 1.7212x; 1.7212x over previous
//
#include <hip/hip_runtime.h>
#include <hip/hip_bf16.h>

#define I_SZ 834
#define H_SZ 190
#define F_SZ 250
#define O_SZ 512
#define T_SZ 256
#define K_SZ 1024   // I+H
#define NW   47500  // F*H: Wupd flat IS W3[1024][47500] row-major

// Abf2 layout: value A[t][k] (bf16 of concat(x_t,h_t)) lives at
//   (k>>3)*2048 + t*8 + (k&7)   -> b128 fragment loads are 256-B coalesced,
//   and 4 consecutive k-slabs = 16 KB contiguous (one K-stage of staging).

typedef __attribute__((ext_vector_type(8))) short short8;
typedef __attribute__((ext_vector_type(4))) float f32x4;

__device__ __forceinline__ short f2bf(float f) {
    union { __hip_bfloat16 h; short s; } u;
    u.h = __float2bfloat16(f);
    return u.s;
}

// async global->LDS, 16B per lane; LDS dest = wave-uniform base + lane*16
__device__ __forceinline__ void gll16(const void* g, void* l) {
    __builtin_amdgcn_global_load_lds(
        (const __attribute__((address_space(1))) void*)g,
        (__attribute__((address_space(3))) void*)l, 16, 0, 0);
}

// -------- K2b: x-part of Abf2 + zero pad k in [834,864) ---------------------
__global__ void __launch_bounds__(256) k2b_buildAx(const float* __restrict__ x,
                                                   short* __restrict__ Abf2) {
    int t = blockIdx.x;
    for (int i = threadIdx.x; i < I_SZ; i += 256)
        Abf2[(i >> 3) * (T_SZ * 8) + t * 8 + (i & 7)] = f2bf(x[t * I_SZ + i]);
    for (int i = I_SZ + threadIdx.x; i < 864; i += 256)
        Abf2[(i >> 3) * (T_SZ * 8) + t * 8 + (i & 7)] = 0;
}

// -------- K1: P^T[h][t] = Wx^T @ x^T via MFMA (12 blocks x 4 waves) ---------
__global__ void __launch_bounds__(256) k1_mfma(const short* __restrict__ Abf2,
                                               const float* __restrict__ Wrnn,
                                               const float* __restrict__ brnn,
                                               float* __restrict__ P) {
    const int tid = threadIdx.x;
    const int bh = blockIdx.x;
    const int w = tid >> 6, l = tid & 63;
    const int l15 = l & 15, lg = l >> 4;
    const int h = bh * 16 + l15;
    const int hc = (h < H_SZ) ? h : H_SZ - 1;

    f32x4 acc[4];
    #pragma unroll
    for (int tt = 0; tt < 4; ++tt) acc[tt] = (f32x4){0.f, 0.f, 0.f, 0.f};

    for (int ks = 0; ks < 27; ++ks) {       // K = 864 (zero-padded past 834)
        short8 afr;
        #pragma unroll
        for (int e = 0; e < 8; ++e) {
            const int kk = ks * 32 + lg * 8 + e;
            float v = (kk < I_SZ && h < H_SZ) ? Wrnn[hc * K_SZ + H_SZ + kk] : 0.f;
            afr[e] = f2bf(v);
        }
        #pragma unroll
        for (int tt = 0; tt < 4; ++tt) {
            const short* ap = Abf2 + (size_t)(ks * 4 + lg) * (T_SZ * 8)
                                   + (size_t)(w * 64 + tt * 16 + l15) * 8;
            short8 bfr = *reinterpret_cast<const short8*>(ap);
            acc[tt] = __builtin_amdgcn_mfma_f32_16x16x32_bf16(afr, bfr, acc[tt], 0, 0, 0);
        }
    }
    #pragma unroll
    for (int tt = 0; tt < 4; ++tt) {
        const int t = w * 64 + tt * 16 + l15;
        #pragma unroll
        for (int r = 0; r < 4; ++r) {
            const int hrow = bh * 16 + lg * 4 + r;
            if (hrow < H_SZ) P[t * H_SZ + hrow] = acc[tt][r] + brnn[hrow];
        }
    }
}

// -------- K2: MFMA scan, 4 waves = 2(n) x 2(k); B[3][6] = 72 VGPR/wave ------
__global__ void __launch_bounds__(256, 1) k2_scan(const float* __restrict__ Wrnn,
                                                  const float* __restrict__ h0,
                                                  const float* __restrict__ P,
                                                  float* __restrict__ h_all,
                                                  float* __restrict__ S,
                                                  short* __restrict__ Abf2) {
    __shared__ __align__(16) short hlds[192];
    __shared__ float part[2][192];
    const int tid = threadIdx.x;
    const int w = tid >> 6, l = tid & 63;
    const int wn = w & 1, wk = w >> 1;
    const int l15 = l & 15, lg = l >> 4;
    const short8 zs = {0, 0, 0, 0, 0, 0, 0, 0};

    short8 B[3][6];
    #pragma unroll
    for (int kt = 0; kt < 3; ++kt) {
        #pragma unroll
        for (int nt = 0; nt < 6; ++nt) {
            const int n = wn * 96 + nt * 16 + l15;
            short8 bf = zs;
            #pragma unroll
            for (int e = 0; e < 8; ++e) {
                const int kk = wk * 96 + kt * 32 + lg * 8 + e;
                float v = (n < H_SZ && kk < H_SZ) ? Wrnn[n * K_SZ + kk] : 0.f;
                bf[e] = f2bf(v);
            }
            B[kt][nt] = bf;
        }
    }
    if (tid < 192) hlds[tid] = f2bf((tid < H_SZ) ? h0[tid] : 0.f);
    float Srun = 0.f;
    float pc = (tid < H_SZ) ? P[tid] : 0.f;
    __syncthreads();

    for (int t = 0; t < T_SZ; ++t) {
        short8 a[3];
        #pragma unroll
        for (int kt = 0; kt < 3; ++kt) {
            short8 ar = *reinterpret_cast<const short8*>(&hlds[wk * 96 + kt * 32 + lg * 8]);
            a[kt] = (l15 == 0) ? ar : zs;
        }
        float pn = (t + 1 < T_SZ && tid < H_SZ) ? P[(t + 1) * H_SZ + tid] : 0.f;
        f32x4 acc[6];
        #pragma unroll
        for (int nt = 0; nt < 6; ++nt) {
            f32x4 c = {0.f, 0.f, 0.f, 0.f};
            #pragma unroll
            for (int kt = 0; kt < 3; ++kt)
                c = __builtin_amdgcn_mfma_f32_16x16x32_bf16(a[kt], B[kt][nt], c, 0, 0, 0);
            acc[nt] = c;
        }
        if (l < 16) {
            #pragma unroll
            for (int nt = 0; nt < 6; ++nt)
                part[wk][wn * 96 + nt * 16 + l] = acc[nt][0];
        }
        __syncthreads();
        if (tid < H_SZ) {
            float v = tanhf(part[0][tid] + part[1][tid] + pc);
            S[t * H_SZ + tid] = Srun;            // prefix EXCLUDING current step
            h_all[t * H_SZ + tid] = v;
            const int k = I_SZ + tid;
            Abf2[(k >> 3) * (T_SZ * 8) + t * 8 + (k & 7)] = f2bf(v);
            hlds[tid] = f2bf(v);
            Srun += v;
        }
        pc = pn;
        __syncthreads();
    }
}

// -------- K3 v5: 2-phase gll-staged MFMA GEMM (zero global loads in K-loop) -
// Block: 128 n-cols (372 blocks), 256 t, BK=32, 32 stages. 8 waves, wave wv
// owns n-tile [bn0+wv*16, +16) x all 256 t (16 MFMA/stage, 64 AGPR acc).
// Per stage: 32 KB staged via 32x global_load_lds(16B); one barrier/stage.
__global__ void __launch_bounds__(512) k3_mfma(const float* __restrict__ Wupd,
                                               const short* __restrict__ Abf2,
                                               const float* __restrict__ S,
                                               float* __restrict__ zprime) {
    __shared__ __align__(16) float Wlds[2][4096];    // [32 k][128 n] fp32
    __shared__ __align__(16) short Alds[2][8192];    // [4 g][256 t][8 k] bf16
    __shared__ float part[2][256];
    const int tid = threadIdx.x;
    const int bn0 = blockIdx.x * 128;
    const int l = tid & 63, wv = tid >> 6;
    const int l15 = l & 15, lg = l >> 4;

    part[tid >> 8][tid & 255] = 0.f;

    // staging setup: 32 chunks of 1 KB; chunk c = wv*4+i. c<16 -> W, else A.
    const char* src[4];
    long long stp[4];
    int cloc[4];
    #pragma unroll
    for (int i = 0; i < 4; ++i) {
        const int c = wv * 4 + i;
        cloc[i] = c;
        if (c < 16) {
            const int k = c * 2 + (l >> 5);          // 0..31
            const int n = (l & 31) * 4;              // 0..124
            const bool ok = (bn0 + n + 4) <= NW;     // NW % 4 == 0
            src[i] = (const char*)(Wupd + (size_t)k * NW + (ok ? (size_t)(bn0 + n) : 0));
            stp[i] = (long long)32 * NW * 4;
        } else {
            src[i] = (const char*)(Abf2 + (size_t)(c - 16) * 512 + (size_t)l * 8);
            stp[i] = 16384;                          // 4 slabs * 4 KB per stage
        }
    }

    f32x4 acc[16];
    #pragma unroll
    for (int tt = 0; tt < 16; ++tt) acc[tt] = (f32x4){0.f, 0.f, 0.f, 0.f};

    // prologue: stage 0 -> buf 0
    #pragma unroll
    for (int i = 0; i < 4; ++i) {
        void* dst = (cloc[i] < 16) ? (void*)&Wlds[0][cloc[i] * 256]
                                   : (void*)&Alds[0][(cloc[i] - 16) * 512];
        gll16(src[i], dst);
        src[i] += stp[i];
    }
    __syncthreads();

    int cur = 0;
    #pragma unroll 1
    for (int s = 0; s < 32; ++s) {
        if (s + 1 < 32) {                            // issue next stage FIRST
            #pragma unroll
            for (int i = 0; i < 4; ++i) {
                void* dst = (cloc[i] < 16) ? (void*)&Wlds[cur ^ 1][cloc[i] * 256]
                                           : (void*)&Alds[cur ^ 1][(cloc[i] - 16) * 512];
                gll16(src[i], dst);
                src[i] += stp[i];
            }
        }
        // compute current tile: pure LDS + MFMA (no global loads!)
        short8 afr;
        #pragma unroll
        for (int e = 0; e < 8; ++e)
            afr[e] = f2bf(Wlds[cur][(lg * 8 + e) * 128 + wv * 16 + l15]);
        #pragma unroll
        for (int tt = 0; tt < 16; ++tt) {
            short8 bfr = *reinterpret_cast<const short8*>(
                &Alds[cur][((size_t)lg * 256 + tt * 16 + l15) * 8]);
            acc[tt] = __builtin_amdgcn_mfma_f32_16x16x32_bf16(afr, bfr, acc[tt], 0, 0, 0);
        }
        __syncthreads();                             // drains staging; cover = compute
        cur ^= 1;
    }

    // epilogue: z'[t][j] += sum_h C^T[n][t] * S[t][h(n)], 2 j-buckets,
    // LDS-reduced across waves, then 512 global atomics per block.
    const int jlo = bn0 / H_SZ;
    #pragma unroll
    for (int tt = 0; tt < 16; ++tt) {
        float p0 = 0.f, p1 = 0.f;
        const int t = tt * 16 + l15;
        #pragma unroll
        for (int r = 0; r < 4; ++r) {
            const int n = bn0 + wv * 16 + lg * 4 + r;
            const bool ok = n < NW;
            const int nc = ok ? n : NW - 1;
            const int j = nc / H_SZ;
            const int h = nc - j * H_SZ;
            const float sv = S[t * H_SZ + h];
            const float prod = ok ? acc[tt][r] * sv : 0.f;
            if (j == jlo) p0 += prod; else p1 += prod;
        }
        p0 += __shfl_xor(p0, 16, 64); p0 += __shfl_xor(p0, 32, 64);
        p1 += __shfl_xor(p1, 16, 64); p1 += __shfl_xor(p1, 32, 64);
        if (lg == 0) {
            if (p0 != 0.f) atomicAdd(&part[0][t], p0);
            if (p1 != 0.f) atomicAdd(&part[1][t], p1);
        }
    }
    __syncthreads();
    {
        const int b = tid >> 8, t = tid & 255;
        const int j = jlo + b;
        const float v = part[b][t];
        if (j < F_SZ && v != 0.f) atomicAdd(&zprime[t * F_SZ + j], v);
    }
}

// -------- K4: z -> selu -> @W2 + b2 -----------------------------------------
__global__ void __launch_bounds__(256) k4_out(const float* __restrict__ x,
                                              const float* __restrict__ h_all,
                                              const float* __restrict__ W1,
                                              const float* __restrict__ bupd,
                                              const float* __restrict__ b1,
                                              const float* __restrict__ W2,
                                              const float* __restrict__ b2,
                                              const float* __restrict__ zprime,
                                              float* __restrict__ out) {
    __shared__ float as[K_SZ];
    __shared__ float ys[256];
    int t = blockIdx.x;
    int tid = threadIdx.x;
    for (int i = tid; i < K_SZ; i += 256)
        as[i] = (i < I_SZ) ? x[t * I_SZ + i] : h_all[t * H_SZ + (i - I_SZ)];
    __syncthreads();
    if (tid < F_SZ) {
        float d1 = 0.f, d2 = 0.f;
        #pragma unroll 4
        for (int i = 0; i < K_SZ; ++i) {
            float av = as[i];
            d1 += av * W1[i * F_SZ + tid];
            d2 += av * bupd[i * F_SZ + tid];
        }
        float z = zprime[t * F_SZ + tid] + d1 + (float)t * d2 + b1[tid];
        const float scale = 1.0507009873554805f, alpha = 1.6732632423543772f;
        ys[tid] = z > 0.f ? scale * z : scale * alpha * (expf(z) - 1.f);
    }
    __syncthreads();
    #pragma unroll
    for (int rep = 0; rep < 2; ++rep) {
        int o = tid + rep * 256;
        float s = 0.f;
        #pragma unroll 2
        for (int jj = 0; jj < F_SZ; ++jj) s += ys[jj] * W2[jj * O_SZ + o];
        out[t * O_SZ + o] = s + b2[o];
    }
}

extern "C" void kernel_launch(void* const* d_in, const int* in_sizes, int n_in,
                              void* d_out, int out_size, void* d_ws, size_t ws_size,
                              hipStream_t stream) {
    const float* x    = (const float*)d_in[0];
    const float* h0   = (const float*)d_in[1];
    const float* Wrnn = (const float*)d_in[2];
    const float* brnn = (const float*)d_in[3];
    const float* Wupd = (const float*)d_in[4];
    const float* bupd = (const float*)d_in[5];
    const float* W1   = (const float*)d_in[6];
    const float* b1   = (const float*)d_in[7];
    const float* W2   = (const float*)d_in[8];
    const float* b2   = (const float*)d_in[9];
    float* out = (float*)d_out;

    float* ws = (float*)d_ws;
    float* P      = ws;                              // 48640
    float* h_all  = P + T_SZ * H_SZ;                 // 48640
    float* S      = h_all + T_SZ * H_SZ;             // 48640
    float* zprime = S + T_SZ * H_SZ;                 // 64000
    short* Abf2   = (short*)(zprime + T_SZ * F_SZ);  // 262144 shorts

    hipMemsetAsync(zprime, 0, T_SZ * F_SZ * sizeof(float), stream);
    k2b_buildAx<<<T_SZ, 256, 0, stream>>>(x, Abf2);
    k1_mfma    <<<12,   256, 0, stream>>>(Abf2, Wrnn, brnn, P);
    k2_scan    <<<1,    256, 0, stream>>>(Wrnn, h0, P, h_all, S, Abf2);
    k3_mfma    <<<372,  512, 0, stream>>>(Wupd, Abf2, S, zprime);
    k4_out     <<<T_SZ, 256, 0, stream>>>(x, h_all, W1, bupd, b1, W2, b2, zprime, out);
}

// Round 9
// 409.034 us; speedup vs baseline: 1.8088x; 1.0509x over previous
//
#include <hip/hip_runtime.h>
#include <hip/hip_bf16.h>

#define I_SZ 834
#define H_SZ 190
#define F_SZ 250
#define O_SZ 512
#define T_SZ 256
#define K_SZ 1024   // I+H
#define NW   47500  // F*H: Wupd flat IS W3[1024][47500] row-major

// Abf2 layout: value A[t][k] (bf16 of concat(x_t,h_t)) lives at
//   (k>>3)*2048 + t*8 + (k&7)   -> b128 fragment loads are 256-B coalesced,
//   and 4 consecutive k-slabs = 16 KB contiguous (one K-stage of staging).

typedef __attribute__((ext_vector_type(8))) short short8;
typedef __attribute__((ext_vector_type(4))) float f32x4;

__device__ __forceinline__ short f2bf(float f) {
    union { __hip_bfloat16 h; short s; } u;
    u.h = __float2bfloat16(f);
    return u.s;
}
__device__ __forceinline__ float bf2f(short s) {
    union { short s; __hip_bfloat16 h; } u;
    u.s = s;
    return __bfloat162float(u.h);
}

// async global->LDS, 16B per lane; LDS dest = wave-uniform base + lane*16
__device__ __forceinline__ void gll16(const void* g, void* l) {
    __builtin_amdgcn_global_load_lds(
        (const __attribute__((address_space(1))) void*)g,
        (__attribute__((address_space(3))) void*)l, 16, 0, 0);
}

// -------- K2b: x-part of Abf2 + zero pad k in [834,864) ---------------------
__global__ void __launch_bounds__(256) k2b_buildAx(const float* __restrict__ x,
                                                   short* __restrict__ Abf2) {
    int t = blockIdx.x;
    for (int i = threadIdx.x; i < I_SZ; i += 256)
        Abf2[(i >> 3) * (T_SZ * 8) + t * 8 + (i & 7)] = f2bf(x[t * I_SZ + i]);
    for (int i = I_SZ + threadIdx.x; i < 864; i += 256)
        Abf2[(i >> 3) * (T_SZ * 8) + t * 8 + (i & 7)] = 0;
}

// -------- K1: P^T[h][t] = Wx^T @ x^T via MFMA (12 blocks x 4 waves) ---------
__global__ void __launch_bounds__(256) k1_mfma(const short* __restrict__ Abf2,
                                               const float* __restrict__ Wrnn,
                                               const float* __restrict__ brnn,
                                               float* __restrict__ P) {
    const int tid = threadIdx.x;
    const int bh = blockIdx.x;
    const int w = tid >> 6, l = tid & 63;
    const int l15 = l & 15, lg = l >> 4;
    const int h = bh * 16 + l15;
    const int hc = (h < H_SZ) ? h : H_SZ - 1;

    f32x4 acc[4];
    #pragma unroll
    for (int tt = 0; tt < 4; ++tt) acc[tt] = (f32x4){0.f, 0.f, 0.f, 0.f};

    for (int ks = 0; ks < 27; ++ks) {       // K = 864 (zero-padded past 834)
        short8 afr;
        #pragma unroll
        for (int e = 0; e < 8; ++e) {
            const int kk = ks * 32 + lg * 8 + e;
            float v = (kk < I_SZ && h < H_SZ) ? Wrnn[hc * K_SZ + H_SZ + kk] : 0.f;
            afr[e] = f2bf(v);
        }
        #pragma unroll
        for (int tt = 0; tt < 4; ++tt) {
            const short* ap = Abf2 + (size_t)(ks * 4 + lg) * (T_SZ * 8)
                                   + (size_t)(w * 64 + tt * 16 + l15) * 8;
            short8 bfr = *reinterpret_cast<const short8*>(ap);
            acc[tt] = __builtin_amdgcn_mfma_f32_16x16x32_bf16(afr, bfr, acc[tt], 0, 0, 0);
        }
    }
    #pragma unroll
    for (int tt = 0; tt < 4; ++tt) {
        const int t = w * 64 + tt * 16 + l15;
        #pragma unroll
        for (int r = 0; r < 4; ++r) {
            const int hrow = bh * 16 + lg * 4 + r;
            if (hrow < H_SZ) P[t * H_SZ + hrow] = acc[tt][r] + brnn[hrow];
        }
    }
}

// -------- K2: MFMA scan, 4 waves = 2(n) x 2(k); B[3][6] = 72 VGPR/wave ------
__global__ void __launch_bounds__(256, 1) k2_scan(const float* __restrict__ Wrnn,
                                                  const float* __restrict__ h0,
                                                  const float* __restrict__ P,
                                                  float* __restrict__ h_all,
                                                  float* __restrict__ S,
                                                  short* __restrict__ Abf2) {
    __shared__ __align__(16) short hlds[192];
    __shared__ float part[2][192];
    const int tid = threadIdx.x;
    const int w = tid >> 6, l = tid & 63;
    const int wn = w & 1, wk = w >> 1;
    const int l15 = l & 15, lg = l >> 4;
    const short8 zs = {0, 0, 0, 0, 0, 0, 0, 0};

    short8 B[3][6];
    #pragma unroll
    for (int kt = 0; kt < 3; ++kt) {
        #pragma unroll
        for (int nt = 0; nt < 6; ++nt) {
            const int n = wn * 96 + nt * 16 + l15;
            short8 bf = zs;
            #pragma unroll
            for (int e = 0; e < 8; ++e) {
                const int kk = wk * 96 + kt * 32 + lg * 8 + e;
                float v = (n < H_SZ && kk < H_SZ) ? Wrnn[n * K_SZ + kk] : 0.f;
                bf[e] = f2bf(v);
            }
            B[kt][nt] = bf;
        }
    }
    if (tid < 192) hlds[tid] = f2bf((tid < H_SZ) ? h0[tid] : 0.f);
    float Srun = 0.f;
    float pc = (tid < H_SZ) ? P[tid] : 0.f;
    __syncthreads();

    for (int t = 0; t < T_SZ; ++t) {
        short8 a[3];
        #pragma unroll
        for (int kt = 0; kt < 3; ++kt) {
            short8 ar = *reinterpret_cast<const short8*>(&hlds[wk * 96 + kt * 32 + lg * 8]);
            a[kt] = (l15 == 0) ? ar : zs;
        }
        float pn = (t + 1 < T_SZ && tid < H_SZ) ? P[(t + 1) * H_SZ + tid] : 0.f;
        f32x4 acc[6];
        #pragma unroll
        for (int nt = 0; nt < 6; ++nt) {
            f32x4 c = {0.f, 0.f, 0.f, 0.f};
            #pragma unroll
            for (int kt = 0; kt < 3; ++kt)
                c = __builtin_amdgcn_mfma_f32_16x16x32_bf16(a[kt], B[kt][nt], c, 0, 0, 0);
            acc[nt] = c;
        }
        if (l < 16) {
            #pragma unroll
            for (int nt = 0; nt < 6; ++nt)
                part[wk][wn * 96 + nt * 16 + l] = acc[nt][0];
        }
        __syncthreads();
        if (tid < H_SZ) {
            float v = tanhf(part[0][tid] + part[1][tid] + pc);
            S[t * H_SZ + tid] = Srun;            // prefix EXCLUDING current step
            h_all[t * H_SZ + tid] = v;
            const int k = I_SZ + tid;
            Abf2[(k >> 3) * (T_SZ * 8) + t * 8 + (k & 7)] = f2bf(v);
            hlds[tid] = f2bf(v);
            Srun += v;
        }
        pc = pn;
        __syncthreads();
    }
}

// -------- K3 v5: 2-phase gll-staged MFMA GEMM (zero global loads in K-loop) -
__global__ void __launch_bounds__(512) k3_mfma(const float* __restrict__ Wupd,
                                               const short* __restrict__ Abf2,
                                               const float* __restrict__ S,
                                               float* __restrict__ zprime) {
    __shared__ __align__(16) float Wlds[2][4096];    // [32 k][128 n] fp32
    __shared__ __align__(16) short Alds[2][8192];    // [4 g][256 t][8 k] bf16
    __shared__ float part[2][256];
    const int tid = threadIdx.x;
    const int bn0 = blockIdx.x * 128;
    const int l = tid & 63, wv = tid >> 6;
    const int l15 = l & 15, lg = l >> 4;

    part[tid >> 8][tid & 255] = 0.f;

    const char* src[4];
    long long stp[4];
    int cloc[4];
    #pragma unroll
    for (int i = 0; i < 4; ++i) {
        const int c = wv * 4 + i;
        cloc[i] = c;
        if (c < 16) {
            const int k = c * 2 + (l >> 5);          // 0..31
            const int n = (l & 31) * 4;              // 0..124
            const bool ok = (bn0 + n + 4) <= NW;     // NW % 4 == 0
            src[i] = (const char*)(Wupd + (size_t)k * NW + (ok ? (size_t)(bn0 + n) : 0));
            stp[i] = (long long)32 * NW * 4;
        } else {
            src[i] = (const char*)(Abf2 + (size_t)(c - 16) * 512 + (size_t)l * 8);
            stp[i] = 16384;
        }
    }

    f32x4 acc[16];
    #pragma unroll
    for (int tt = 0; tt < 16; ++tt) acc[tt] = (f32x4){0.f, 0.f, 0.f, 0.f};

    #pragma unroll
    for (int i = 0; i < 4; ++i) {
        void* dst = (cloc[i] < 16) ? (void*)&Wlds[0][cloc[i] * 256]
                                   : (void*)&Alds[0][(cloc[i] - 16) * 512];
        gll16(src[i], dst);
        src[i] += stp[i];
    }
    __syncthreads();

    int cur = 0;
    #pragma unroll 1
    for (int s = 0; s < 32; ++s) {
        if (s + 1 < 32) {                            // issue next stage FIRST
            #pragma unroll
            for (int i = 0; i < 4; ++i) {
                void* dst = (cloc[i] < 16) ? (void*)&Wlds[cur ^ 1][cloc[i] * 256]
                                           : (void*)&Alds[cur ^ 1][(cloc[i] - 16) * 512];
                gll16(src[i], dst);
                src[i] += stp[i];
            }
        }
        short8 afr;
        #pragma unroll
        for (int e = 0; e < 8; ++e)
            afr[e] = f2bf(Wlds[cur][(lg * 8 + e) * 128 + wv * 16 + l15]);
        #pragma unroll
        for (int tt = 0; tt < 16; ++tt) {
            short8 bfr = *reinterpret_cast<const short8*>(
                &Alds[cur][((size_t)lg * 256 + tt * 16 + l15) * 8]);
            acc[tt] = __builtin_amdgcn_mfma_f32_16x16x32_bf16(afr, bfr, acc[tt], 0, 0, 0);
        }
        __syncthreads();
        cur ^= 1;
    }

    const int jlo = bn0 / H_SZ;
    #pragma unroll
    for (int tt = 0; tt < 16; ++tt) {
        float p0 = 0.f, p1 = 0.f;
        const int t = tt * 16 + l15;
        #pragma unroll
        for (int r = 0; r < 4; ++r) {
            const int n = bn0 + wv * 16 + lg * 4 + r;
            const bool ok = n < NW;
            const int nc = ok ? n : NW - 1;
            const int j = nc / H_SZ;
            const int h = nc - j * H_SZ;
            const float sv = S[t * H_SZ + h];
            const float prod = ok ? acc[tt][r] * sv : 0.f;
            if (j == jlo) p0 += prod; else p1 += prod;
        }
        p0 += __shfl_xor(p0, 16, 64); p0 += __shfl_xor(p0, 32, 64);
        p1 += __shfl_xor(p1, 16, 64); p1 += __shfl_xor(p1, 32, 64);
        if (lg == 0) {
            if (p0 != 0.f) atomicAdd(&part[0][t], p0);
            if (p1 != 0.f) atomicAdd(&part[1][t], p1);
        }
    }
    __syncthreads();
    {
        const int b = tid >> 8, t = tid & 255;
        const int j = jlo + b;
        const float v = part[b][t];
        if (j < F_SZ && v != 0.f) atomicAdd(&zprime[t * F_SZ + j], v);
    }
}

// -------- K4a: z = zprime + A@W1 + t*(A@bupd) + b1 -> SELU -> ys (bf16 slab)
// 16 blocks (j-tile of 16) x 4 waves (t-quarter of 64). C^T[j][t].
// bupd hi/lo split: d2 error stays ~fp24 so t*d2 (t<=255) stays accurate.
__global__ void __launch_bounds__(256) k4a_mfma(const short* __restrict__ Abf2,
                                                const float* __restrict__ W1,
                                                const float* __restrict__ bupd,
                                                const float* __restrict__ b1,
                                                const float* __restrict__ zprime,
                                                short* __restrict__ ysb) {
    const int tid = threadIdx.x;
    const int j0 = blockIdx.x * 16;
    const int w = tid >> 6, l = tid & 63;
    const int l15 = l & 15, lg = l >> 4;
    const int j = j0 + l15;
    const int jc = (j < F_SZ) ? j : F_SZ - 1;

    f32x4 acc1[4], acch[4], accl[4];
    #pragma unroll
    for (int tt = 0; tt < 4; ++tt) {
        acc1[tt] = (f32x4){0.f, 0.f, 0.f, 0.f};
        acch[tt] = (f32x4){0.f, 0.f, 0.f, 0.f};
        accl[tt] = (f32x4){0.f, 0.f, 0.f, 0.f};
    }

    for (int ks = 0; ks < 32; ++ks) {
        short8 a1, ah, al;
        #pragma unroll
        for (int e = 0; e < 8; ++e) {
            const int kk = ks * 32 + lg * 8 + e;
            a1[e] = f2bf(W1[kk * F_SZ + jc]);
            const float bu = bupd[kk * F_SZ + jc];
            const short hi = f2bf(bu);
            ah[e] = hi;
            al[e] = f2bf(bu - bf2f(hi));
        }
        #pragma unroll
        for (int tt = 0; tt < 4; ++tt) {
            const short* ap = Abf2 + (size_t)(ks * 4 + lg) * (T_SZ * 8)
                                   + (size_t)(w * 64 + tt * 16 + l15) * 8;
            short8 bfr = *reinterpret_cast<const short8*>(ap);
            acc1[tt] = __builtin_amdgcn_mfma_f32_16x16x32_bf16(a1, bfr, acc1[tt], 0, 0, 0);
            acch[tt] = __builtin_amdgcn_mfma_f32_16x16x32_bf16(ah, bfr, acch[tt], 0, 0, 0);
            accl[tt] = __builtin_amdgcn_mfma_f32_16x16x32_bf16(al, bfr, accl[tt], 0, 0, 0);
        }
    }
    const float scale = 1.0507009873554805f, alpha = 1.6732632423543772f;
    #pragma unroll
    for (int tt = 0; tt < 4; ++tt) {
        const int t = w * 64 + tt * 16 + l15;     // C col
        #pragma unroll
        for (int r = 0; r < 4; ++r) {
            const int jr = j0 + lg * 4 + r;       // C row
            short sv = 0;
            if (jr < F_SZ) {
                const float d2 = acch[tt][r] + accl[tt][r];
                float z = zprime[t * F_SZ + jr] + acc1[tt][r] + (float)t * d2 + b1[jr];
                float y = z > 0.f ? scale * z : scale * alpha * (expf(z) - 1.f);
                sv = f2bf(y);
            }
            ysb[(jr >> 3) * (T_SZ * 8) + t * 8 + (jr & 7)] = sv;   // jr < 256 always
        }
    }
}

// -------- K4b: out^T[o][t] = W2^T @ ys^T + b2. 16 blocks x 4 waves ----------
__global__ void __launch_bounds__(256) k4b_mfma(const short* __restrict__ ysb,
                                                const float* __restrict__ W2,
                                                const float* __restrict__ b2,
                                                float* __restrict__ out) {
    const int tid = threadIdx.x;
    const int o0 = (blockIdx.x & 7) * 64;     // o-group
    const int th = blockIdx.x >> 3;           // t-half
    const int w = tid >> 6, l = tid & 63;
    const int l15 = l & 15, lg = l >> 4;
    const int o = o0 + w * 16 + l15;

    f32x4 acc[8];
    #pragma unroll
    for (int tt = 0; tt < 8; ++tt) acc[tt] = (f32x4){0.f, 0.f, 0.f, 0.f};

    for (int ks = 0; ks < 8; ++ks) {          // K = 256 (250 real + 6 zero)
        short8 afr;
        #pragma unroll
        for (int e = 0; e < 8; ++e) {
            const int kk = ks * 32 + lg * 8 + e;
            afr[e] = (kk < F_SZ) ? f2bf(W2[kk * O_SZ + o]) : (short)0;
        }
        #pragma unroll
        for (int tt = 0; tt < 8; ++tt) {
            const short* ap = ysb + (size_t)(ks * 4 + lg) * (T_SZ * 8)
                                  + (size_t)(th * 128 + tt * 16 + l15) * 8;
            short8 bfr = *reinterpret_cast<const short8*>(ap);
            acc[tt] = __builtin_amdgcn_mfma_f32_16x16x32_bf16(afr, bfr, acc[tt], 0, 0, 0);
        }
    }
    #pragma unroll
    for (int tt = 0; tt < 8; ++tt) {
        const int t = th * 128 + tt * 16 + l15;
        #pragma unroll
        for (int r = 0; r < 4; ++r) {
            const int oo = o0 + w * 16 + lg * 4 + r;
            out[t * O_SZ + oo] = acc[tt][r] + b2[oo];
        }
    }
}

extern "C" void kernel_launch(void* const* d_in, const int* in_sizes, int n_in,
                              void* d_out, int out_size, void* d_ws, size_t ws_size,
                              hipStream_t stream) {
    const float* x    = (const float*)d_in[0];
    const float* h0   = (const float*)d_in[1];
    const float* Wrnn = (const float*)d_in[2];
    const float* brnn = (const float*)d_in[3];
    const float* Wupd = (const float*)d_in[4];
    const float* bupd = (const float*)d_in[5];
    const float* W1   = (const float*)d_in[6];
    const float* b1   = (const float*)d_in[7];
    const float* W2   = (const float*)d_in[8];
    const float* b2   = (const float*)d_in[9];
    float* out = (float*)d_out;

    float* ws = (float*)d_ws;
    float* P      = ws;                              // 48640
    float* h_all  = P + T_SZ * H_SZ;                 // 48640
    float* S      = h_all + T_SZ * H_SZ;             // 48640
    float* zprime = S + T_SZ * H_SZ;                 // 64000
    short* Abf2   = (short*)(zprime + T_SZ * F_SZ);  // 262144 shorts
    short* ysb    = Abf2 + 262144;                   // 65536 shorts (128 KB)

    hipMemsetAsync(zprime, 0, T_SZ * F_SZ * sizeof(float), stream);
    k2b_buildAx<<<T_SZ, 256, 0, stream>>>(x, Abf2);
    k1_mfma    <<<12,   256, 0, stream>>>(Abf2, Wrnn, brnn, P);
    k2_scan    <<<1,    256, 0, stream>>>(Wrnn, h0, P, h_all, S, Abf2);
    k3_mfma    <<<372,  512, 0, stream>>>(Wupd, Abf2, S, zprime);
    k4a_mfma   <<<16,   256, 0, stream>>>(Abf2, W1, bupd, b1, zprime, ysb);
    k4b_mfma   <<<16,   256, 0, stream>>>(ysb, W2, b2, out);
}